// Round 2
// baseline (579.866 us; speedup 1.0000x reference)
//
#include <hip/hip_runtime.h>
#include <math.h>

#define NBIN 25
#define T 256
#define PAD 27
#define ROWS_PER_CHUNK 384
#define ACC_ROWS 64   // 4 waves * 2 halves * 8 designated lanes

// ws layout per batch b (stride 64 floats):
//   [0..24] num_per_bin, [25..49] den_per_bin, [50] label sum

__global__ __launch_bounds__(256, 8)
void qap_accum(const float* __restrict__ qX, const float* __restrict__ dXs,
               const int* __restrict__ labels, float* __restrict__ ws,
               int N, int nChunks) {
    __shared__ float accN[ACC_ROWS * PAD];
    __shared__ float accD[ACC_ROWS * PAD];
    __shared__ float labLds[ROWS_PER_CHUNK];
    __shared__ float part[4 * 64];

    const int tid  = threadIdx.x;
    const int b    = blockIdx.x / nChunks;
    const int chunk= blockIdx.x % nChunks;
    const int wave = tid >> 6;
    const int lane = tid & 63;
    const int half = lane >> 5;
    const int sub  = lane & 31;

    const int n0   = chunk * ROWS_PER_CHUNK;
    const int n1   = min(n0 + ROWS_PER_CHUNK, N);
    const int rows = n1 - n0;

    for (int i = tid; i < ACC_ROWS * PAD; i += T) { accN[i] = 0.f; accD[i] = 0.f; }
    for (int i = tid; i < rows; i += T)
        labLds[i] = (float)labels[(size_t)b * N + n0 + i];

    // query fragment (lane sub owns elements 4*sub..4*sub+3) + query norm
    const float4 qv = reinterpret_cast<const float4*>(qX + b * 128)[sub];
    float qs = qv.x*qv.x + qv.y*qv.y + qv.z*qv.z + qv.w*qv.w;
    #pragma unroll
    for (int mk = 1; mk <= 16; mk <<= 1) qs += __shfl_xor(qs, mk);
    const float qn = fmaxf(sqrtf(qs), 1e-8f);
    __syncthreads();

    float labCnt = 0.f;
    const int accRowBase = (wave << 4) + (half << 3);
    const float* dbase = dXs + (size_t)b * N * 128;

    int r = n0 + (wave << 1) + half;          // uniform across the 32-lane half
    bool act = r < n1;
    float4 x = make_float4(0.f, 0.f, 0.f, 0.f);
    if (act) x = reinterpret_cast<const float4*>(dbase + (size_t)r * 128)[sub];

    int it = 0;
    while (act) {
        const int rn = r + 8;
        const bool actn = rn < n1;
        float4 xn = make_float4(0.f, 0.f, 0.f, 0.f);
        if (actn) xn = reinterpret_cast<const float4*>(dbase + (size_t)rn * 128)[sub];

        float dot = x.x*qv.x + x.y*qv.y + x.z*qv.z + x.w*qv.w;
        float nr  = x.x*x.x  + x.y*x.y  + x.z*x.z  + x.w*x.w;
        #pragma unroll
        for (int mk = 1; mk <= 16; mk <<= 1) {
            dot += __shfl_xor(dot, mk);
            nr  += __shfl_xor(nr,  mk);
        }
        if (sub == (it & 7)) {
            const float dn  = fmaxf(sqrtf(nr), 1e-8f);
            const float sim = dot / (qn * dn);
            float p = fminf(fmaxf((1.f - sim) * 12.f, 0.f), 24.f);
            int m = (int)p; if (m > 24) m = 24;
            const float frac = p - (float)m;
            const float lab  = labLds[r - n0];
            labCnt += lab;
            const float w0 = 1.f - frac;
            const int ba = (accRowBase + sub) * PAD;
            accD[ba + m] += w0;
            accN[ba + m] += lab * w0;
            if (m + 1 < NBIN) {
                accD[ba + m + 1] += frac;
                accN[ba + m + 1] += lab * frac;
            }
        }
        r = rn; act = actn; x = xn; ++it;
    }
    if (sub < 8) accD[(accRowBase + sub) * PAD + 25] = labCnt;
    __syncthreads();

    const int c = tid & 63, g = tid >> 6;
    if (c < 51) {
        const int idx = (c < 25) ? c : ((c < 50) ? (c - 25) : 25);
        const float* arr = (c < 25) ? accN : accD;
        float s = 0.f;
        #pragma unroll
        for (int t = g * 16; t < g * 16 + 16; ++t) s += arr[t * PAD + idx];
        part[g * 64 + c] = s;
    }
    __syncthreads();
    if (tid < 51)
        atomicAdd(&ws[b * 64 + tid],
                  part[tid] + part[64 + tid] + part[128 + tid] + part[192 + tid]);
}

__global__ void qap_final(const float* __restrict__ ws, float* __restrict__ out, int B) {
    const int lane = threadIdx.x;
    float ap = 0.f;
    if (lane < B) {
        const float* w = ws + lane * 64;
        const float labSum = w[50];
        float cn = 0.f, cd = 0.f;
        for (int k = 0; k < NBIN; ++k) {
            const float nk = w[k];
            const float dk = w[25 + k];
            cn += nk;
            cd += dk;
            const float prec = cn / (1e-16f + cd);
            const float rec  = nk / labSum;
            ap = fmaf(prec, rec, ap);
        }
    }
    for (int off = 32; off > 0; off >>= 1) ap += __shfl_down(ap, off);
    if (lane == 0) out[0] = ap / (float)B;
}

extern "C" void kernel_launch(void* const* d_in, const int* in_sizes, int n_in,
                              void* d_out, int out_size, void* d_ws, size_t ws_size,
                              hipStream_t stream) {
    const float* qX     = (const float*)d_in[0];
    const float* dXs    = (const float*)d_in[1];
    const int*   labels = (const int*)d_in[2];
    float* out = (float*)d_out;
    float* ws  = (float*)d_ws;

    const int M = in_sizes[1] / in_sizes[2];      // 128
    const int B = in_sizes[0] / M;                // 16
    const int N = in_sizes[2] / B;                // 50000
    (void)M;

    const int nChunks = (N + ROWS_PER_CHUNK - 1) / ROWS_PER_CHUNK;

    hipMemsetAsync(ws, 0, (size_t)B * 64 * sizeof(float), stream);
    qap_accum<<<B * nChunks, T, 0, stream>>>(qX, dXs, labels, ws, N, nChunks);
    qap_final<<<1, 64, 0, stream>>>(ws, out, B);
}

// Round 3
// 556.443 us; speedup vs baseline: 1.0421x; 1.0421x over previous
//
#include <hip/hip_runtime.h>
#include <math.h>

#define NBIN 25
#define T 256
#define PAD 27
#define RPC 512                 // rows per chunk/block
#define UNROLL 4
#define GROUPS (RPC / (8 * UNROLL))   // 16 groups; 8 half-waves per block

// ws layout per batch b (stride 64 floats):
//   [0..24] num_per_bin, [25..49] den_per_bin, [50] label sum

__global__ __launch_bounds__(256, 4)
void qap_accum(const float* __restrict__ qX, const float* __restrict__ dXs,
               const int* __restrict__ labels, float* __restrict__ ws,
               int N, int nChunks) {
    __shared__ float accN[32 * PAD];
    __shared__ float accD[32 * PAD];
    __shared__ float labLds[RPC];
    __shared__ float part[4 * 64];

    const int tid     = threadIdx.x;
    const int b       = blockIdx.x / nChunks;
    const int chunk   = blockIdx.x % nChunks;
    const int sub     = tid & 31;
    const int halfIdx = tid >> 5;          // 0..7

    const int n0   = chunk * RPC;
    const int n1   = min(n0 + RPC, N);
    const int rows = n1 - n0;

    for (int i = tid; i < 32 * PAD; i += T) { accN[i] = 0.f; accD[i] = 0.f; }
    for (int i = tid; i < rows; i += T)
        labLds[i] = (float)labels[(size_t)b * N + n0 + i];

    // query fragment + norm (butterfly within 32-lane half)
    const float4 qv = reinterpret_cast<const float4*>(qX + b * 128)[sub];
    float qs = qv.x*qv.x + qv.y*qv.y + qv.z*qv.z + qv.w*qv.w;
    #pragma unroll
    for (int mk = 1; mk <= 16; mk <<= 1) qs += __shfl_xor(qs, mk);
    const float qn = fmaxf(sqrtf(qs), 1e-8f);
    __syncthreads();

    const float* dbase = dXs + (size_t)b * N * 128;
    float labCnt = 0.f;

    float4 xc[UNROLL], xn[UNROLL];

    // rows for (group g, slot j): r = n0 + halfIdx + 8*(UNROLL*g + j)
    #pragma unroll
    for (int j = 0; j < UNROLL; ++j) {
        const int r = n0 + halfIdx + 8 * j;
        xc[j] = make_float4(0.f, 0.f, 0.f, 0.f);
        if (r < n1)
            xc[j] = reinterpret_cast<const float4*>(dbase + (size_t)r * 128)[sub];
    }

    #pragma unroll 1
    for (int g = 0; g < GROUPS; ++g) {
        // prefetch next group
        if (g + 1 < GROUPS) {
            #pragma unroll
            for (int j = 0; j < UNROLL; ++j) {
                const int r = n0 + halfIdx + 8 * (UNROLL * (g + 1) + j);
                xn[j] = make_float4(0.f, 0.f, 0.f, 0.f);
                if (r < n1)
                    xn[j] = reinterpret_cast<const float4*>(dbase + (size_t)r * 128)[sub];
            }
        }

        float dt[UNROLL], nr[UNROLL];
        #pragma unroll
        for (int j = 0; j < UNROLL; ++j) {
            dt[j] = xc[j].x*qv.x + xc[j].y*qv.y + xc[j].z*qv.z + xc[j].w*qv.w;
            nr[j] = xc[j].x*xc[j].x + xc[j].y*xc[j].y + xc[j].z*xc[j].z + xc[j].w*xc[j].w;
        }
        #pragma unroll
        for (int mk = 1; mk <= 16; mk <<= 1) {
            #pragma unroll
            for (int j = 0; j < UNROLL; ++j) {
                dt[j] += __shfl_xor(dt[j], mk);
                nr[j] += __shfl_xor(nr[j], mk);
            }
        }

        // lane j (0..3) of each half owns result j
        const float d01 = (sub & 1) ? dt[1] : dt[0];
        const float d23 = (sub & 1) ? dt[3] : dt[2];
        const float dsel = (sub & 2) ? d23 : d01;
        const float n01 = (sub & 1) ? nr[1] : nr[0];
        const float n23 = (sub & 1) ? nr[3] : nr[2];
        const float nsel = (sub & 2) ? n23 : n01;

        if (sub < UNROLL) {
            const int r = n0 + halfIdx + 8 * (UNROLL * g + sub);
            if (r < n1) {
                const float dn  = fmaxf(sqrtf(nsel), 1e-8f);
                const float sim = dsel / (qn * dn);
                float p = fminf(fmaxf((1.f - sim) * 12.f, 0.f), 24.f);
                int m = (int)p; if (m > 24) m = 24;
                const float frac = p - (float)m;
                const float lab  = labLds[r - n0];
                labCnt += lab;
                const float w0 = 1.f - frac;
                const int ba = (halfIdx * 4 + sub) * PAD;
                accD[ba + m] += w0;
                accN[ba + m] += lab * w0;
                if (m + 1 < NBIN) {
                    accD[ba + m + 1] += frac;
                    accN[ba + m + 1] += lab * frac;
                }
            }
        }

        #pragma unroll
        for (int j = 0; j < UNROLL; ++j) xc[j] = xn[j];
    }

    if (sub < UNROLL) accD[(halfIdx * 4 + sub) * PAD + 25] = labCnt;
    __syncthreads();

    // block reduction: 51 columns over 32 accumulator rows, 4-way row split
    const int c = tid & 63, g4 = tid >> 6;
    if (c < 51) {
        const int idx = (c < 25) ? c : ((c < 50) ? (c - 25) : 25);
        const float* arr = (c < 25) ? accN : accD;
        float s = 0.f;
        #pragma unroll
        for (int t = g4 * 8; t < g4 * 8 + 8; ++t) s += arr[t * PAD + idx];
        part[g4 * 64 + c] = s;
    }
    __syncthreads();
    if (tid < 51)
        atomicAdd(&ws[b * 64 + tid],
                  part[tid] + part[64 + tid] + part[128 + tid] + part[192 + tid]);
}

__global__ void qap_final(const float* __restrict__ ws, float* __restrict__ out, int B) {
    const int lane = threadIdx.x;
    float ap = 0.f;
    if (lane < B) {
        const float* w = ws + lane * 64;
        const float labSum = w[50];
        float cn = 0.f, cd = 0.f;
        for (int k = 0; k < NBIN; ++k) {
            const float nk = w[k];
            const float dk = w[25 + k];
            cn += nk;
            cd += dk;
            const float prec = cn / (1e-16f + cd);
            const float rec  = nk / labSum;
            ap = fmaf(prec, rec, ap);
        }
    }
    for (int off = 32; off > 0; off >>= 1) ap += __shfl_down(ap, off);
    if (lane == 0) out[0] = ap / (float)B;
}

extern "C" void kernel_launch(void* const* d_in, const int* in_sizes, int n_in,
                              void* d_out, int out_size, void* d_ws, size_t ws_size,
                              hipStream_t stream) {
    const float* qX     = (const float*)d_in[0];
    const float* dXs    = (const float*)d_in[1];
    const int*   labels = (const int*)d_in[2];
    float* out = (float*)d_out;
    float* ws  = (float*)d_ws;

    const int M = in_sizes[1] / in_sizes[2];      // 128
    const int B = in_sizes[0] / M;                // 16
    const int N = in_sizes[2] / B;                // 50000
    (void)M;

    const int nChunks = (N + RPC - 1) / RPC;      // 98

    hipMemsetAsync(ws, 0, (size_t)B * 64 * sizeof(float), stream);
    qap_accum<<<B * nChunks, T, 0, stream>>>(qX, dXs, labels, ws, N, nChunks);
    qap_final<<<1, 64, 0, stream>>>(ws, out, B);
}